// Round 15
// baseline (53.145 us; speedup 1.0000x reference)
//
#include <hip/hip_runtime.h>
#include <hip/hip_bf16.h>
#include <stdint.h>

#define LL 2048   // sequence length
#define NB 16     // batch
#define DD 256    // din = dout
#define NT2 16    // K-tiles (2048/128 bytes) in agg

typedef __bf16 bf16x8 __attribute__((ext_vector_type(8)));
typedef float f32x4 __attribute__((ext_vector_type(4)));
typedef int i32x4 __attribute__((ext_vector_type(4)));
typedef int i32x8 __attribute__((ext_vector_type(8)));
union Frag8 { i32x8 v8; i32x4 v4[2]; };

__device__ __forceinline__ unsigned short f2bf(float f) {
    __hip_bfloat16 h = __float2bfloat16(f);   // RNE
    return *reinterpret_cast<unsigned short*>(&h);
}

// ---- fp8 e4m3fn helpers -----------------------------------------------------
#if __has_builtin(__builtin_amdgcn_cvt_pk_fp8_f32)
__device__ __forceinline__ uint32_t pk4fp8(float a, float b, float c, float d) {
    int r = 0;
    r = __builtin_amdgcn_cvt_pk_fp8_f32(a, b, r, false);
    r = __builtin_amdgcn_cvt_pk_fp8_f32(c, d, r, true);
    return (uint32_t)r;
}
#else
__device__ __forceinline__ uint32_t f2fp8_1(float f) {
    uint32_t u = __float_as_uint(f);
    uint32_t s = (u >> 24) & 0x80u;
    uint32_t au = u & 0x7FFFFFFFu;
    float af = __uint_as_float(au);
    if (af >= 448.0f) return s | 0x7Eu;
    if (af < 0x1p-6f) {
        uint32_t q = (uint32_t)rintf(af * 512.0f);
        return s | q;
    }
    uint32_t r = au + (0x7FFFFu + ((au >> 20) & 1u));
    uint32_t e8 = (r >> 23) - 120u;
    return s | (e8 << 3) | ((r >> 20) & 7u);
}
__device__ __forceinline__ uint32_t pk4fp8(float a, float b, float c, float d) {
    return f2fp8_1(a) | (f2fp8_1(b) << 8) | (f2fp8_1(c) << 16) | (f2fp8_1(d) << 24);
}
#endif

__device__ __forceinline__ float fp8tof(uint32_t b) {
    uint32_t s = (b & 0x80u) << 24;
    uint32_t e = (b >> 3) & 15u, m = b & 7u;
    float v = (e == 0) ? (float)m * 0x1p-9f
            : __uint_as_float(((e + 120u) << 23) | (m << 20));
    return __uint_as_float(__float_as_uint(v) | s);
}

__device__ __forceinline__ void gload16(const void* g, void* l) {
    __builtin_amdgcn_global_load_lds(
        (const __attribute__((address_space(1))) void*)g,
        (__attribute__((address_space(3))) void*)l,
        16, 0, 0);
}

#define DSREAD(dst, off) asm volatile("ds_read_b128 %0, %1" : "=v"(dst) : "v"(off))

// ---------------------------------------------------------------------------
// Kernel 1: degree -> dinv, graph f32 -> fp8 (exact 0/1), non-temporal graph
// loads. Blocks r<256 also fold in prep_w: Wt[o][r] = bf16(W[r][o]).
// ---------------------------------------------------------------------------
__global__ __launch_bounds__(256) void prep_graph(
        const float* __restrict__ graph, float* __restrict__ dinv,
        uint8_t* __restrict__ gq,
        const float* __restrict__ W, unsigned short* __restrict__ Wt) {
    int r = blockIdx.x;
    int t = threadIdx.x;
    const f32x4* row = (const f32x4*)(graph + (size_t)r * LL);
    f32x4 v0 = __builtin_nontemporal_load(row + t * 2 + 0);
    f32x4 v1 = __builtin_nontemporal_load(row + t * 2 + 1);
    float s = v0[0] + v0[1] + v0[2] + v0[3] + v1[0] + v1[1] + v1[2] + v1[3];

    uint32_t lo = (v0[0] != 0.f ? 0x38u : 0u) | ((v0[1] != 0.f ? 0x38u : 0u) << 8)
                | ((v0[2] != 0.f ? 0x38u : 0u) << 16) | ((v0[3] != 0.f ? 0x38u : 0u) << 24);
    uint32_t hi = (v1[0] != 0.f ? 0x38u : 0u) | ((v1[1] != 0.f ? 0x38u : 0u) << 8)
                | ((v1[2] != 0.f ? 0x38u : 0u) << 16) | ((v1[3] != 0.f ? 0x38u : 0u) << 24);
    *(uint2*)(gq + (size_t)r * LL + t * 8) = make_uint2(lo, hi);

    if (r < DD) Wt[(size_t)t * DD + r] = f2bf(W[(size_t)r * DD + t]);

    #pragma unroll
    for (int off = 32; off > 0; off >>= 1) s += __shfl_down(s, off, 64);
    __shared__ float red[4];
    if ((t & 63) == 0) red[t >> 6] = s;
    __syncthreads();
    if (t == 0) {
        float deg = red[0] + red[1] + red[2] + red[3] + 1.0f;  // + self loop
        dinv[r] = 1.0f / sqrtf(deg);
    }
}

// ---------------------------------------------------------------------------
// Kernel 3 v3: Pq[b*256+o][m] = fp8(dinv[m]*sum x*W). 256 blocks x 512 thr.
// A-tile (128x256 f32 -> bf16) staged in ONE upfront burst: 16 f32x4 loads
// per thread issued back-to-back (128KB/CU in flight) -> one exposed HBM
// latency instead of four barrier-separated chunks. Al[128][256] bf16 with
// low-3-bit slot XOR swizzle (slot^(row&7)); B dbuf via gload16 as proven.
// ---------------------------------------------------------------------------
__global__ __launch_bounds__(512) void linear_kernel(
        const float* __restrict__ x, const unsigned short* __restrict__ Wt,
        const float* __restrict__ dinv, uint8_t* __restrict__ Pq) {
    __shared__ __align__(16) unsigned short Al[128][256];    // 64 KB
    __shared__ __align__(16) unsigned short Bl[2][256][64];  // 64 KB
    const int t = threadIdx.x;
    const int w = t >> 6, ln = t & 63;
    const int wm = w >> 2, wn = w & 3;
    const int lr = ln & 15, lg = ln >> 4;
    const int s7 = lr & 7;
    const int m0 = blockIdx.x * 128;
    const int b = m0 >> 11, ml0 = m0 & (LL - 1);

    const int rtb = t >> 3, stb = (t & 7) ^ (rtb & 7);   // B stage: row, swz src slot
    const int wd = w * 512;                              // ushort units per wave round

    f32x4 acc[4][4] = {};

    #define L_STAGE_B(buf, k0) { \
        _Pragma("unroll") \
        for (int r = 0; r < 4; ++r) \
            gload16(Wt + (size_t)(rtb + 64 * r) * DD + (k0) + stb * 8, \
                    &Bl[buf][r * 64][0] + wd); }

    // ---- A: one burst of 16 loads/thread (chunk c = q*512 + t of 4096) ----
    f32x4 xa[16];
    #pragma unroll
    for (int q = 0; q < 8; ++q) {
        int c = q * 512 + t;
        int row = c >> 5, slot = c & 31;                 // 16B-dest chunks
        const float* src = x + (size_t)(m0 + row) * DD + slot * 8;
        xa[q * 2]     = *(const f32x4*)(src);
        xa[q * 2 + 1] = *(const f32x4*)(src + 4);
    }
    L_STAGE_B(0, 0);
    #pragma unroll
    for (int q = 0; q < 8; ++q) {
        int c = q * 512 + t;
        int row = c >> 5, slot = c & 31;
        int sl = (slot ^ (row & 7)) * 8;                 // low-3-bit XOR, bijective
        f32x4 u0 = xa[q * 2], u1 = xa[q * 2 + 1];
        *(ushort4*)&Al[row][sl]     = make_ushort4(f2bf(u0[0]), f2bf(u0[1]), f2bf(u0[2]), f2bf(u0[3]));
        *(ushort4*)&Al[row][sl + 4] = make_ushort4(f2bf(u1[0]), f2bf(u1[1]), f2bf(u1[2]), f2bf(u1[3]));
    }
    __syncthreads();

    for (int it = 0; it < 4; ++it) {
        const int cb = it & 1;
        if (it < 3) L_STAGE_B(cb ^ 1, (it + 1) * 64);
        #pragma unroll
        for (int ks = 0; ks < 2; ++ks) {
            bf16x8 fa[4], fb[4];
            #pragma unroll
            for (int i = 0; i < 4; ++i)
                fa[i] = *(const bf16x8*)&Al[wm * 64 + i * 16 + lr]
                        [(it * 8 + ((ks * 4 + lg) ^ s7)) * 8];
            #pragma unroll
            for (int j = 0; j < 4; ++j)
                fb[j] = *(const bf16x8*)&Bl[cb][wn * 64 + j * 16 + lr][((ks * 4 + lg) ^ s7) * 8];
            #pragma unroll
            for (int i = 0; i < 4; ++i)
                #pragma unroll
                for (int j = 0; j < 4; ++j)
                    acc[i][j] = __builtin_amdgcn_mfma_f32_16x16x32_bf16(
                        fa[i], fb[j], acc[i][j], 0, 0, 0);
        }
        __syncthreads();
    }

    #pragma unroll
    for (int i = 0; i < 4; ++i) {
        int ml = ml0 + wm * 64 + i * 16 + lg * 4;
        float4 dv = *(const float4*)(dinv + ml);
        #pragma unroll
        for (int j = 0; j < 4; ++j) {
            int o = wn * 64 + j * 16 + lr;
            uint32_t pk = pk4fp8(dv.x * acc[i][j][0], dv.y * acc[i][j][1],
                                 dv.z * acc[i][j][2], dv.w * acc[i][j][3]);
            *(uint32_t*)(Pq + ((size_t)(b * DD + o)) * LL + ml) = pk;
        }
    }
}

// ---------------------------------------------------------------------------
// Kernel 4 (R13/R14-proven): agg = gq @ Pq^T in MX-fp8 (scale=1.0).
// BM=BN=128, BK=128B, 4 waves 2x2, 256 thr, dbuf 64KB, 512 blocks = 2
// independent barrier domains/CU. asm DSREAD keeps frags in registers.
// Coalesced LDS-round-trip epilogue with NT out-stores.
// ---------------------------------------------------------------------------
__global__ __launch_bounds__(256, 2) void agg_kernel(
        const uint8_t* __restrict__ gq, const uint8_t* __restrict__ Pq,
        const float* __restrict__ dinv, const float* __restrict__ bias,
        const float* __restrict__ x, float* __restrict__ out) {
    // main loop: 2 x 32KB buffers; epilogue reuses as float[128][132] (66KB)
    __shared__ __align__(16) unsigned char lds[128 * 132 * 4];

    const int t = threadIdx.x;
    const int w = t >> 6, ln = t & 63;
    const int wm = w >> 1, wn = w & 1;          // 2x2 wave grid
    const int lr = ln & 15, lg = ln >> 4;
    const int s7 = lr & 7;

    // XCD swizzle: 64 contiguous wgs/XCD = 16 l-tiles x 4 n'-tiles
    int bid = blockIdx.x;
    int wg = (bid & 7) * 64 + (bid >> 3);
    const int l0 = (wg & 15) * 128;
    const int n0 = (wg >> 4) * 128;

    // staging source (pre-swizzled global: slot_src = slot_lin ^ (row&7))
    const int rt8 = t >> 3;                     // 0..31 (row within 32-row round)
    const int st = (t & 7) ^ (rt8 & 7);
    const uint8_t* ag = gq + (size_t)(l0 + rt8) * LL + st * 16;
    const uint8_t* bg = Pq + (size_t)(n0 + rt8) * LL + st * 16;
    const int wd = w * 1024;                    // wave-uniform LDS dst (bytes)

    f32x4 acc[4][4] = {};

    // prologue: stage K-tile 0 into buf 0
    #pragma unroll
    for (int r = 0; r < 4; ++r) {
        gload16(ag + (size_t)(32 * r) * LL, lds + r * 4096 + wd);
        gload16(bg + (size_t)(32 * r) * LL, lds + 16384 + r * 4096 + wd);
    }
    asm volatile("s_waitcnt vmcnt(0)" ::: "memory");
    __builtin_amdgcn_s_barrier();

    for (int it = 0; it < NT2; ++it) {
        const int cb = (it & 1) * 32768;        // compute buffer
        const int sb = cb ^ 32768;              // stage buffer

        // issue next tile's loads first (they complete under this iter's work)
        if (it + 1 < NT2) {
            const int ko = (it + 1) * 128;
            #pragma unroll
            for (int r = 0; r < 4; ++r) {
                gload16(ag + (size_t)(32 * r) * LL + ko, lds + sb + r * 4096 + wd);
                gload16(bg + (size_t)(32 * r) * LL + ko, lds + sb + 16384 + r * 4096 + wd);
            }
        }

        Frag8 fa[4], fb[4];
        #pragma unroll
        for (int i = 0; i < 4; ++i)
            #pragma unroll
            for (int h = 0; h < 2; ++h) {
                int off = cb + (wm * 64 + i * 16 + lr) * 128
                        + (((lg * 2 + h) ^ s7) << 4);
                DSREAD(fa[i].v4[h], off);
            }
        #pragma unroll
        for (int j = 0; j < 4; ++j)
            #pragma unroll
            for (int h = 0; h < 2; ++h) {
                int off = cb + 16384 + (wn * 64 + j * 16 + lr) * 128
                        + (((lg * 2 + h) ^ s7) << 4);
                DSREAD(fb[j].v4[h], off);
            }
        asm volatile("s_waitcnt lgkmcnt(0)" ::: "memory");
        __builtin_amdgcn_sched_barrier(0);
        __builtin_amdgcn_s_setprio(1);
        #pragma unroll
        for (int i = 0; i < 4; ++i)
            #pragma unroll
            for (int j = 0; j < 4; ++j)
                acc[i][j] = __builtin_amdgcn_mfma_scale_f32_16x16x128_f8f6f4(
                    fa[i].v8, fb[j].v8, acc[i][j], 0, 0, 0, 127, 0, 127);
        __builtin_amdgcn_s_setprio(0);
        __builtin_amdgcn_sched_barrier(0);
        asm volatile("s_waitcnt vmcnt(0)" ::: "memory");  // next buffer staged
        __builtin_amdgcn_s_barrier();
    }

    // ========== epilogue phase A: relu(dinv*(S+pv)+bias) -> LDS ==========
    float (*ldsF)[132] = (float(*)[132])lds;
    const int b = n0 >> 8;
    #pragma unroll
    for (int j = 0; j < 4; ++j) {
        int np = n0 + wn * 64 + j * 16 + lr;
        int o = np & (DD - 1);
        float bo = bias[o];
        int oloc = wn * 64 + j * 16 + lr;
        #pragma unroll
        for (int i = 0; i < 4; ++i) {
            int lloc = wm * 64 + i * 16 + lg * 4;        // local row 0..127
            float4 dv = *(const float4*)(dinv + l0 + lloc);
            uchar4 pv = *(const uchar4*)(Pq + (size_t)np * LL + l0 + lloc);
            float dva[4] = {dv.x, dv.y, dv.z, dv.w};
            float pva[4] = {fp8tof(pv.x), fp8tof(pv.y), fp8tof(pv.z), fp8tof(pv.w)};
            #pragma unroll
            for (int r = 0; r < 4; ++r) {
                float aggv = dva[r] * (acc[i][j][r] + pva[r]) + bo;
                ldsF[lloc + r][oloc] = fmaxf(aggv, 0.0f);
            }
        }
    }
    __syncthreads();

    // ========== epilogue phase B: coalesced +x and NT store ==========
    const int row0 = t >> 5, c4 = (t & 31) * 4;
    const size_t obase = ((size_t)(b * LL + l0)) * DD + (n0 & (DD - 1));
    #pragma unroll
    for (int it2 = 0; it2 < 16; ++it2) {
        int row = it2 * 8 + row0;
        f32x4 xv = *(const f32x4*)(x + obase + (size_t)row * DD + c4);
        f32x4 sv = *(const f32x4*)&ldsF[row][c4];
        f32x4 ov = sv + xv;
        __builtin_nontemporal_store(ov, (f32x4*)(out + obase + (size_t)row * DD + c4));
    }
}

// ---------------------------------------------------------------------------
extern "C" void kernel_launch(void* const* d_in, const int* in_sizes, int n_in,
                              void* d_out, int out_size, void* d_ws, size_t ws_size,
                              hipStream_t stream) {
    const float* x     = (const float*)d_in[0];   // [16,2048,256]
    const float* graph = (const float*)d_in[1];   // [1,2048,2048]
    const float* W     = (const float*)d_in[2];   // [256,256]
    const float* bias  = (const float*)d_in[3];   // [256]
    float* out = (float*)d_out;

    char* ws = (char*)d_ws;
    float*          dinv = (float*)ws;                                   // 8 KB
    uint8_t*        gq   = (uint8_t*)(ws + 8192);                        // 4 MB
    unsigned short* Wt   = (unsigned short*)(ws + 8192 + 4194304);       // 128 KB
    uint8_t*        Pq   = (uint8_t*)(ws + 8192 + 4194304 + 131072);     // 8 MB

    prep_graph<<<LL, 256, 0, stream>>>(graph, dinv, gq, W, Wt);
    linear_kernel<<<256, 512, 0, stream>>>(x, Wt, dinv, Pq);
    agg_kernel<<<512, 256, 0, stream>>>(gq, Pq, dinv, bias, x, out);
}

// Round 16
// 52.472 us; speedup vs baseline: 1.0128x; 1.0128x over previous
//
#include <hip/hip_runtime.h>
#include <hip/hip_bf16.h>
#include <stdint.h>

#define LL 2048   // sequence length
#define NB 16     // batch
#define DD 256    // din = dout
#define NT2 16    // K-tiles (2048/128 bytes) in agg

typedef __bf16 bf16x8 __attribute__((ext_vector_type(8)));
typedef float f32x4 __attribute__((ext_vector_type(4)));
typedef int i32x4 __attribute__((ext_vector_type(4)));
typedef int i32x8 __attribute__((ext_vector_type(8)));
union Frag8 { i32x8 v8; i32x4 v4[2]; };

__device__ __forceinline__ unsigned short f2bf(float f) {
    __hip_bfloat16 h = __float2bfloat16(f);   // RNE
    return *reinterpret_cast<unsigned short*>(&h);
}

// ---- fp8 e4m3fn helpers -----------------------------------------------------
#if __has_builtin(__builtin_amdgcn_cvt_pk_fp8_f32)
__device__ __forceinline__ uint32_t pk4fp8(float a, float b, float c, float d) {
    int r = 0;
    r = __builtin_amdgcn_cvt_pk_fp8_f32(a, b, r, false);
    r = __builtin_amdgcn_cvt_pk_fp8_f32(c, d, r, true);
    return (uint32_t)r;
}
#else
__device__ __forceinline__ uint32_t f2fp8_1(float f) {
    uint32_t u = __float_as_uint(f);
    uint32_t s = (u >> 24) & 0x80u;
    uint32_t au = u & 0x7FFFFFFFu;
    float af = __uint_as_float(au);
    if (af >= 448.0f) return s | 0x7Eu;
    if (af < 0x1p-6f) {
        uint32_t q = (uint32_t)rintf(af * 512.0f);
        return s | q;
    }
    uint32_t r = au + (0x7FFFFu + ((au >> 20) & 1u));
    uint32_t e8 = (r >> 23) - 120u;
    return s | (e8 << 3) | ((r >> 20) & 7u);
}
__device__ __forceinline__ uint32_t pk4fp8(float a, float b, float c, float d) {
    return f2fp8_1(a) | (f2fp8_1(b) << 8) | (f2fp8_1(c) << 16) | (f2fp8_1(d) << 24);
}
#endif

__device__ __forceinline__ float fp8tof(uint32_t b) {
    uint32_t s = (b & 0x80u) << 24;
    uint32_t e = (b >> 3) & 15u, m = b & 7u;
    float v = (e == 0) ? (float)m * 0x1p-9f
            : __uint_as_float(((e + 120u) << 23) | (m << 20));
    return __uint_as_float(__float_as_uint(v) | s);
}

__device__ __forceinline__ void gload16(const void* g, void* l) {
    __builtin_amdgcn_global_load_lds(
        (const __attribute__((address_space(1))) void*)g,
        (__attribute__((address_space(3))) void*)l,
        16, 0, 0);
}

#define DSREAD(dst, off) asm volatile("ds_read_b128 %0, %1" : "=v"(dst) : "v"(off))

// ---------------------------------------------------------------------------
// Kernel 1: degree -> dinv, graph f32 -> fp8 (exact 0/1), non-temporal graph
// loads. Blocks r<256 also fold in prep_w: Wt[o][r] = bf16(W[r][o]).
// ---------------------------------------------------------------------------
__global__ __launch_bounds__(256) void prep_graph(
        const float* __restrict__ graph, float* __restrict__ dinv,
        uint8_t* __restrict__ gq,
        const float* __restrict__ W, unsigned short* __restrict__ Wt) {
    int r = blockIdx.x;
    int t = threadIdx.x;
    const f32x4* row = (const f32x4*)(graph + (size_t)r * LL);
    f32x4 v0 = __builtin_nontemporal_load(row + t * 2 + 0);
    f32x4 v1 = __builtin_nontemporal_load(row + t * 2 + 1);
    float s = v0[0] + v0[1] + v0[2] + v0[3] + v1[0] + v1[1] + v1[2] + v1[3];

    uint32_t lo = (v0[0] != 0.f ? 0x38u : 0u) | ((v0[1] != 0.f ? 0x38u : 0u) << 8)
                | ((v0[2] != 0.f ? 0x38u : 0u) << 16) | ((v0[3] != 0.f ? 0x38u : 0u) << 24);
    uint32_t hi = (v1[0] != 0.f ? 0x38u : 0u) | ((v1[1] != 0.f ? 0x38u : 0u) << 8)
                | ((v1[2] != 0.f ? 0x38u : 0u) << 16) | ((v1[3] != 0.f ? 0x38u : 0u) << 24);
    *(uint2*)(gq + (size_t)r * LL + t * 8) = make_uint2(lo, hi);

    if (r < DD) Wt[(size_t)t * DD + r] = f2bf(W[(size_t)r * DD + t]);

    #pragma unroll
    for (int off = 32; off > 0; off >>= 1) s += __shfl_down(s, off, 64);
    __shared__ float red[4];
    if ((t & 63) == 0) red[t >> 6] = s;
    __syncthreads();
    if (t == 0) {
        float deg = red[0] + red[1] + red[2] + red[3] + 1.0f;  // + self loop
        dinv[r] = 1.0f / sqrtf(deg);
    }
}

// ---------------------------------------------------------------------------
// Kernel 3 v2 (proven, R14-best): Pq[b*256+o][m] = fp8(dinv[m]*sum x*W)
// 256 blocks x 512 thr: block = 128 rows x all 256 o -> x read exactly once.
// ---------------------------------------------------------------------------
__global__ __launch_bounds__(512) void linear_kernel(
        const float* __restrict__ x, const unsigned short* __restrict__ Wt,
        const float* __restrict__ dinv, uint8_t* __restrict__ Pq) {
    __shared__ __align__(16) unsigned short Al[2][128][64];
    __shared__ __align__(16) unsigned short Bl[2][256][64];
    const int t = threadIdx.x;
    const int w = t >> 6, ln = t & 63;
    const int wm = w >> 2, wn = w & 3;
    const int lr = ln & 15, lg = ln >> 4;
    const int s7 = lr & 7;
    const int m0 = blockIdx.x * 128;
    const int b = m0 >> 11, ml0 = m0 & (LL - 1);

    const int rt2 = t >> 2, c2 = (t & 3) * 2;            // A stage: row, slot pair
    const int rtb = t >> 3, stb = (t & 7) ^ (rtb & 7);   // B stage: row, swz src slot
    const int wd = w * 512;                              // ushort units per wave round

    f32x4 acc[4][4] = {};

    #define L_STAGE_A(buf, k0) { \
        const float* xs = x + (size_t)(m0 + rt2) * DD + (k0) + (t & 3) * 16; \
        float4 u0 = *(const float4*)(xs + 0); \
        float4 u1 = *(const float4*)(xs + 4); \
        float4 u2 = *(const float4*)(xs + 8); \
        float4 u3 = *(const float4*)(xs + 12); \
        int sl0 = (c2 ^ (rt2 & 7)) * 8, sl1 = ((c2 + 1) ^ (rt2 & 7)) * 8; \
        *(ushort4*)&Al[buf][rt2][sl0]     = make_ushort4(f2bf(u0.x), f2bf(u0.y), f2bf(u0.z), f2bf(u0.w)); \
        *(ushort4*)&Al[buf][rt2][sl0 + 4] = make_ushort4(f2bf(u1.x), f2bf(u1.y), f2bf(u1.z), f2bf(u1.w)); \
        *(ushort4*)&Al[buf][rt2][sl1]     = make_ushort4(f2bf(u2.x), f2bf(u2.y), f2bf(u2.z), f2bf(u2.w)); \
        *(ushort4*)&Al[buf][rt2][sl1 + 4] = make_ushort4(f2bf(u3.x), f2bf(u3.y), f2bf(u3.z), f2bf(u3.w)); }

    #define L_STAGE_B(buf, k0) { \
        _Pragma("unroll") \
        for (int r = 0; r < 4; ++r) \
            gload16(Wt + (size_t)(rtb + 64 * r) * DD + (k0) + stb * 8, \
                    &Bl[buf][r * 64][0] + wd); }

    L_STAGE_A(0, 0); L_STAGE_B(0, 0);
    __syncthreads();

    for (int it = 0; it < 4; ++it) {
        const int cb = it & 1;
        if (it < 3) { L_STAGE_A(cb ^ 1, (it + 1) * 64); L_STAGE_B(cb ^ 1, (it + 1) * 64); }
        #pragma unroll
        for (int ks = 0; ks < 2; ++ks) {
            bf16x8 fa[4], fb[4];
            #pragma unroll
            for (int i = 0; i < 4; ++i)
                fa[i] = *(const bf16x8*)&Al[cb][wm * 64 + i * 16 + lr][((ks * 4 + lg) ^ s7) * 8];
            #pragma unroll
            for (int j = 0; j < 4; ++j)
                fb[j] = *(const bf16x8*)&Bl[cb][wn * 64 + j * 16 + lr][((ks * 4 + lg) ^ s7) * 8];
            #pragma unroll
            for (int i = 0; i < 4; ++i)
                #pragma unroll
                for (int j = 0; j < 4; ++j)
                    acc[i][j] = __builtin_amdgcn_mfma_f32_16x16x32_bf16(
                        fa[i], fb[j], acc[i][j], 0, 0, 0);
        }
        __syncthreads();
    }

    #pragma unroll
    for (int i = 0; i < 4; ++i) {
        int ml = ml0 + wm * 64 + i * 16 + lg * 4;
        float4 dv = *(const float4*)(dinv + ml);
        #pragma unroll
        for (int j = 0; j < 4; ++j) {
            int o = wn * 64 + j * 16 + lr;
            uint32_t pk = pk4fp8(dv.x * acc[i][j][0], dv.y * acc[i][j][1],
                                 dv.z * acc[i][j][2], dv.w * acc[i][j][3]);
            *(uint32_t*)(Pq + ((size_t)(b * DD + o)) * LL + ml) = pk;
        }
    }
}

// ---------------------------------------------------------------------------
// Kernel 4 (R13/R14-proven): agg = gq @ Pq^T in MX-fp8 (scale=1.0).
// BM=BN=128, BK=128B, 4 waves 2x2, 256 thr, dbuf 64KB, 512 blocks = 2
// independent barrier domains/CU. asm DSREAD keeps frags in registers.
// Coalesced LDS-round-trip epilogue with NT out-stores.
// ---------------------------------------------------------------------------
__global__ __launch_bounds__(256, 2) void agg_kernel(
        const uint8_t* __restrict__ gq, const uint8_t* __restrict__ Pq,
        const float* __restrict__ dinv, const float* __restrict__ bias,
        const float* __restrict__ x, float* __restrict__ out) {
    // main loop: 2 x 32KB buffers; epilogue reuses as float[128][132] (66KB)
    __shared__ __align__(16) unsigned char lds[128 * 132 * 4];

    const int t = threadIdx.x;
    const int w = t >> 6, ln = t & 63;
    const int wm = w >> 1, wn = w & 1;          // 2x2 wave grid
    const int lr = ln & 15, lg = ln >> 4;
    const int s7 = lr & 7;

    // XCD swizzle: 64 contiguous wgs/XCD = 16 l-tiles x 4 n'-tiles
    int bid = blockIdx.x;
    int wg = (bid & 7) * 64 + (bid >> 3);
    const int l0 = (wg & 15) * 128;
    const int n0 = (wg >> 4) * 128;

    // staging source (pre-swizzled global: slot_src = slot_lin ^ (row&7))
    const int rt8 = t >> 3;                     // 0..31 (row within 32-row round)
    const int st = (t & 7) ^ (rt8 & 7);
    const uint8_t* ag = gq + (size_t)(l0 + rt8) * LL + st * 16;
    const uint8_t* bg = Pq + (size_t)(n0 + rt8) * LL + st * 16;
    const int wd = w * 1024;                    // wave-uniform LDS dst (bytes)

    f32x4 acc[4][4] = {};

    // prologue: stage K-tile 0 into buf 0
    #pragma unroll
    for (int r = 0; r < 4; ++r) {
        gload16(ag + (size_t)(32 * r) * LL, lds + r * 4096 + wd);
        gload16(bg + (size_t)(32 * r) * LL, lds + 16384 + r * 4096 + wd);
    }
    asm volatile("s_waitcnt vmcnt(0)" ::: "memory");
    __builtin_amdgcn_s_barrier();

    for (int it = 0; it < NT2; ++it) {
        const int cb = (it & 1) * 32768;        // compute buffer
        const int sb = cb ^ 32768;              // stage buffer

        // issue next tile's loads first (they complete under this iter's work)
        if (it + 1 < NT2) {
            const int ko = (it + 1) * 128;
            #pragma unroll
            for (int r = 0; r < 4; ++r) {
                gload16(ag + (size_t)(32 * r) * LL + ko, lds + sb + r * 4096 + wd);
                gload16(bg + (size_t)(32 * r) * LL + ko, lds + sb + 16384 + r * 4096 + wd);
            }
        }

        Frag8 fa[4], fb[4];
        #pragma unroll
        for (int i = 0; i < 4; ++i)
            #pragma unroll
            for (int h = 0; h < 2; ++h) {
                int off = cb + (wm * 64 + i * 16 + lr) * 128
                        + (((lg * 2 + h) ^ s7) << 4);
                DSREAD(fa[i].v4[h], off);
            }
        #pragma unroll
        for (int j = 0; j < 4; ++j)
            #pragma unroll
            for (int h = 0; h < 2; ++h) {
                int off = cb + 16384 + (wn * 64 + j * 16 + lr) * 128
                        + (((lg * 2 + h) ^ s7) << 4);
                DSREAD(fb[j].v4[h], off);
            }
        asm volatile("s_waitcnt lgkmcnt(0)" ::: "memory");
        __builtin_amdgcn_sched_barrier(0);
        __builtin_amdgcn_s_setprio(1);
        #pragma unroll
        for (int i = 0; i < 4; ++i)
            #pragma unroll
            for (int j = 0; j < 4; ++j)
                acc[i][j] = __builtin_amdgcn_mfma_scale_f32_16x16x128_f8f6f4(
                    fa[i].v8, fb[j].v8, acc[i][j], 0, 0, 0, 127, 0, 127);
        __builtin_amdgcn_s_setprio(0);
        __builtin_amdgcn_sched_barrier(0);
        asm volatile("s_waitcnt vmcnt(0)" ::: "memory");  // next buffer staged
        __builtin_amdgcn_s_barrier();
    }

    // ========== epilogue phase A: relu(dinv*(S+pv)+bias) -> LDS ==========
    float (*ldsF)[132] = (float(*)[132])lds;
    const int b = n0 >> 8;
    #pragma unroll
    for (int j = 0; j < 4; ++j) {
        int np = n0 + wn * 64 + j * 16 + lr;
        int o = np & (DD - 1);
        float bo = bias[o];
        int oloc = wn * 64 + j * 16 + lr;
        #pragma unroll
        for (int i = 0; i < 4; ++i) {
            int lloc = wm * 64 + i * 16 + lg * 4;        // local row 0..127
            float4 dv = *(const float4*)(dinv + l0 + lloc);
            uchar4 pv = *(const uchar4*)(Pq + (size_t)np * LL + l0 + lloc);
            float dva[4] = {dv.x, dv.y, dv.z, dv.w};
            float pva[4] = {fp8tof(pv.x), fp8tof(pv.y), fp8tof(pv.z), fp8tof(pv.w)};
            #pragma unroll
            for (int r = 0; r < 4; ++r) {
                float aggv = dva[r] * (acc[i][j][r] + pva[r]) + bo;
                ldsF[lloc + r][oloc] = fmaxf(aggv, 0.0f);
            }
        }
    }
    __syncthreads();

    // ========== epilogue phase B: coalesced +x and NT store ==========
    const int row0 = t >> 5, c4 = (t & 31) * 4;
    const size_t obase = ((size_t)(b * LL + l0)) * DD + (n0 & (DD - 1));
    #pragma unroll
    for (int it2 = 0; it2 < 16; ++it2) {
        int row = it2 * 8 + row0;
        f32x4 xv = *(const f32x4*)(x + obase + (size_t)row * DD + c4);
        f32x4 sv = *(const f32x4*)&ldsF[row][c4];
        f32x4 ov = sv + xv;
        __builtin_nontemporal_store(ov, (f32x4*)(out + obase + (size_t)row * DD + c4));
    }
}

// ---------------------------------------------------------------------------
extern "C" void kernel_launch(void* const* d_in, const int* in_sizes, int n_in,
                              void* d_out, int out_size, void* d_ws, size_t ws_size,
                              hipStream_t stream) {
    const float* x     = (const float*)d_in[0];   // [16,2048,256]
    const float* graph = (const float*)d_in[1];   // [1,2048,2048]
    const float* W     = (const float*)d_in[2];   // [256,256]
    const float* bias  = (const float*)d_in[3];   // [256]
    float* out = (float*)d_out;

    char* ws = (char*)d_ws;
    float*          dinv = (float*)ws;                                   // 8 KB
    uint8_t*        gq   = (uint8_t*)(ws + 8192);                        // 4 MB
    unsigned short* Wt   = (unsigned short*)(ws + 8192 + 4194304);       // 128 KB
    uint8_t*        Pq   = (uint8_t*)(ws + 8192 + 4194304 + 131072);     // 8 MB

    prep_graph<<<LL, 256, 0, stream>>>(graph, dinv, gq, W, Wt);
    linear_kernel<<<256, 512, 0, stream>>>(x, Wt, dinv, Pq);
    agg_kernel<<<512, 256, 0, stream>>>(gq, Pq, dinv, bias, x, out);
}